// Round 9
// baseline (256.588 us; speedup 1.0000x reference)
//
#include <hip/hip_runtime.h>
#include <math.h>

typedef __attribute__((ext_vector_type(8))) short bf16x8;
typedef __attribute__((ext_vector_type(4))) float f32x4;

__device__ __forceinline__ unsigned short f2b(float f) {
    unsigned int u = __float_as_uint(f);
    unsigned int r = (u + 0x7fffu + ((u >> 16) & 1u)) >> 16;   // RTNE
    return (unsigned short)r;
}
__device__ __forceinline__ float blo(unsigned int w) { return __uint_as_float(w << 16); }
__device__ __forceinline__ float bhi(unsigned int w) { return __uint_as_float(w & 0xffff0000u); }
__device__ __forceinline__ float b2f(unsigned short u) { return __uint_as_float((unsigned int)u << 16); }

__device__ __forceinline__ void gload_lds16(const void* g, void* lds) {
    __builtin_amdgcn_global_load_lds(
        (const __attribute__((address_space(1))) unsigned int*)g,
        (__attribute__((address_space(3))) unsigned int*)lds, 16, 0, 0);
}

// ---------------------------------------------------------------------------
// bf16 MFMA GEMM: out[M x NC] = epi(A[Mpad x K] @ W[K x NC] + bias)
// BT = W^T row-major [NC x K] bf16. Tile 128x128, BK=64, 4 waves, T2 swizzle.
// Single-buffered LDS (32 KB) -- 64KB double-buffer costs occupancy (r6).
// EPI: 1 = relu -> bf16 ws (unguarded, Mpad rows)
//      2 = bias -> bf16 ws (unguarded, Mpad rows)
//      3 = +res(f32) + LayerNorm -> bf16 ws (pad rows zeroed)   [NC==128]
//      4 = +res(bf16) + LayerNorm -> f32 out (guard row<M)      [NC==128]
// ---------------------------------------------------------------------------
template<int K, int EPI>
__global__ __launch_bounds__(256)
void mfma_gemm(const unsigned short* __restrict__ A,
               const unsigned short* __restrict__ BT,
               const float* __restrict__ bias,
               const void* __restrict__ res,
               const float* __restrict__ lng,
               const float* __restrict__ lnb,
               void* __restrict__ outv, int M, int NC)
{
    __shared__ unsigned short As[128 * 64];
    __shared__ unsigned short Bs[128 * 64];
    const int tid  = threadIdx.x;
    const int lane = tid & 63;
    const int wid  = tid >> 6;
    const int wr = wid >> 1, wc = wid & 1;
    const int rowBase = blockIdx.x * 128;
    const int colBase = blockIdx.y * 128;

    f32x4 acc[4][4];
#pragma unroll
    for (int i = 0; i < 4; ++i)
#pragma unroll
        for (int j = 0; j < 4; ++j) acc[i][j] = (f32x4)0.f;

    int srow[4], skoff[4];
#pragma unroll
    for (int t = 0; t < 4; ++t) {
        int c = tid + t * 256;
        int r = c >> 3, cc = c & 7;
        srow[t]  = r;
        skoff[t] = ((cc ^ (r & 7)) << 3);
    }

    const int rl = lane & 15;
    const int kh = lane >> 4;

    for (int k0 = 0; k0 < K; k0 += 64) {
#pragma unroll
        for (int t = 0; t < 4; ++t) {
            int c = tid + t * 256;
            gload_lds16(A + (size_t)(rowBase + srow[t]) * K + k0 + skoff[t], &As[c * 8]);
            gload_lds16(BT + (size_t)(colBase + srow[t]) * K + k0 + skoff[t], &Bs[c * 8]);
        }
        __syncthreads();

        bf16x8 a[4][2], b[4][2];
#pragma unroll
        for (int mi = 0; mi < 4; ++mi)
#pragma unroll
            for (int kt = 0; kt < 2; ++kt) {
                a[mi][kt] = *(const bf16x8*)&As[(((wr * 64 + mi * 16 + rl) * 64) + kt * 32 + kh * 8) ^ ((rl & 7) << 3)];
                b[mi][kt] = *(const bf16x8*)&Bs[(((wc * 64 + mi * 16 + rl) * 64) + kt * 32 + kh * 8) ^ ((rl & 7) << 3)];
            }
#pragma unroll
        for (int kt = 0; kt < 2; ++kt)
#pragma unroll
            for (int mi = 0; mi < 4; ++mi)
#pragma unroll
                for (int ni = 0; ni < 4; ++ni)
                    acc[mi][ni] = __builtin_amdgcn_mfma_f32_16x16x32_bf16(a[mi][kt], b[ni][kt], acc[mi][ni], 0, 0, 0);
        __syncthreads();
    }

    if (EPI == 3 || EPI == 4) {
        float* ls = (float*)As;
        float bb[4], gg[4], be[4];
#pragma unroll
        for (int ni = 0; ni < 4; ++ni) {
            int col = wc * 64 + ni * 16 + rl;
            bb[ni] = bias[col];
            gg[ni] = lng[col];
            be[ni] = lnb[col];
        }
#pragma unroll
        for (int mi = 0; mi < 4; ++mi) {
#pragma unroll
            for (int r = 0; r < 4; ++r) {
                int lrow = wr * 64 + mi * 16 + kh * 4 + r;
                int row  = rowBase + lrow;
                float s = 0.f, ss = 0.f;
#pragma unroll
                for (int ni = 0; ni < 4; ++ni) {
                    int col = wc * 64 + ni * 16 + rl;
                    float rr = 0.f;
                    if (row < M) {
                        if (EPI == 3) rr = ((const float*)res)[(size_t)row * 128 + col];
                        else          rr = b2f(((const unsigned short*)res)[(size_t)row * 128 + col]);
                    }
                    float v = acc[mi][ni][r] + bb[ni] + rr;
                    acc[mi][ni][r] = v;
                    s += v; ss += v * v;
                }
#pragma unroll
                for (int off = 1; off < 16; off <<= 1) {
                    s  += __shfl_xor(s,  off, 64);
                    ss += __shfl_xor(ss, off, 64);
                }
                if (rl == 0) {
                    ls[lrow * 2 + wc]       = s;
                    ls[256 + lrow * 2 + wc] = ss;
                }
            }
        }
        __syncthreads();
#pragma unroll
        for (int mi = 0; mi < 4; ++mi) {
#pragma unroll
            for (int r = 0; r < 4; ++r) {
                int lrow = wr * 64 + mi * 16 + kh * 4 + r;
                int row  = rowBase + lrow;
                float s  = ls[lrow * 2] + ls[lrow * 2 + 1];
                float ss = ls[256 + lrow * 2] + ls[256 + lrow * 2 + 1];
                float mean = s * (1.f / 128.f);
                float var  = ss * (1.f / 128.f) - mean * mean;
                float rstd = rsqrtf(var + 1e-5f);
#pragma unroll
                for (int ni = 0; ni < 4; ++ni) {
                    int col = wc * 64 + ni * 16 + rl;
                    float o = (acc[mi][ni][r] - mean) * rstd * gg[ni] + be[ni];
                    if (EPI == 3) {
                        ((unsigned short*)outv)[(size_t)row * 128 + col] = (row < M) ? f2b(o) : (unsigned short)0;
                    } else {
                        if (row < M) ((float*)outv)[(size_t)row * 128 + col] = o;
                    }
                }
            }
        }
    } else {
#pragma unroll
        for (int ni = 0; ni < 4; ++ni) {
            const int col = colBase + wc * 64 + ni * 16 + rl;
            const float bv = bias[col];
#pragma unroll
            for (int mi = 0; mi < 4; ++mi) {
                const int rowb = rowBase + wr * 64 + mi * 16 + kh * 4;
#pragma unroll
                for (int r = 0; r < 4; ++r) {
                    float v = acc[mi][ni][r] + bv;
                    if (EPI == 1) v = fmaxf(v, 0.f);
                    ((unsigned short*)outv)[(size_t)(rowb + r) * NC + col] = f2b(v);
                }
            }
        }
    }
}

// ---------------------------------------------------------------------------
// fused: x cast | weight cast/transpose | per-chunk edge histograms (bhist)
// grid = xblocks + 768 + gblocks
// ---------------------------------------------------------------------------
#define EPB 8192   // edges per histogram/grouping block

__global__ void cast_all(const float* __restrict__ x, unsigned short* __restrict__ xb,
                         int n, int npad, int xblocks,
                         const float* __restrict__ Wq, const float* __restrict__ Wk,
                         const float* __restrict__ Wv, const float* __restrict__ Wo,
                         const float* __restrict__ W1, const float* __restrict__ W2,
                         const float* __restrict__ bq, const float* __restrict__ bk,
                         const float* __restrict__ bv,
                         unsigned short* __restrict__ WcatT, unsigned short* __restrict__ WoT,
                         unsigned short* __restrict__ W1T, unsigned short* __restrict__ W2T,
                         float* __restrict__ bqkv,
                         const int* __restrict__ tgt, int* __restrict__ bhist,
                         int E, int nb)
{
    __shared__ int hist[1024];
    if (blockIdx.x < (unsigned)xblocks) {
        size_t i = ((size_t)blockIdx.x * 256 + threadIdx.x) * 4;
        if (i >= (size_t)npad * 128) return;
        float4 v = make_float4(0.f, 0.f, 0.f, 0.f);
        if (i < (size_t)n * 128) v = *(const float4*)(x + i);
        ushort4 o;
        o.x = f2b(v.x); o.y = f2b(v.y); o.z = f2b(v.z); o.w = f2b(v.w);
        *(ushort4*)(xb + i) = o;
        return;
    }
    if (blockIdx.x < (unsigned)(xblocks + 768)) {
        int i = (blockIdx.x - xblocks) * 256 + threadIdx.x;
        if (i < 49152) {
            int j = i >> 7, k = i & 127;
            const float* W = (j < 128) ? Wq : ((j < 256) ? Wk : Wv);
            WcatT[i] = f2b(W[k * 128 + (j & 127)]);
        } else if (i < 65536) {
            int t = i - 49152; int j = t >> 7, k = t & 127;
            WoT[t] = f2b(Wo[k * 128 + j]);
        } else if (i < 131072) {
            int t = i - 65536; int j = t >> 7, k = t & 127;
            W1T[t] = f2b(W1[k * 512 + j]);
        } else if (i < 196608) {
            int t = i - 131072; int j = t >> 9, k = t & 511;
            W2T[t] = f2b(W2[k * 128 + j]);
        }
        if (i < 384) bqkv[i] = (i < 128) ? bq[i] : ((i < 256) ? bk[i - 128] : bv[i - 256]);
        return;
    }
    // per-chunk histogram (no global atomics, no pre-zero)
    int cb = blockIdx.x - xblocks - 768;
    int base = cb * EPB;
    for (int i = threadIdx.x; i < nb; i += 256) hist[i] = 0;
    __syncthreads();
    int end = min(base + EPB, E);
    for (int e = base + threadIdx.x; e < end; e += 256)
        atomicAdd(&hist[tgt[e] >> 6], 1);
    __syncthreads();
    for (int i = threadIdx.x; i < nb; i += 256)
        bhist[cb * 1024 + i] = hist[i];
}

// ---------------------------------------------------------------------------
// column-sum bhist + exclusive scan -> bstart/bcur
// ---------------------------------------------------------------------------
__global__ __launch_bounds__(256)
void bucket_scan(const int* __restrict__ bhist, int* __restrict__ bstart,
                 int* __restrict__ bcur, int nb, int gb, int E)
{
    __shared__ int colsum[1024];
    int tid = threadIdx.x;
    for (int i = tid; i < nb; i += 256) {
        int v = 0;
        for (int g = 0; g < gb; ++g) v += bhist[g * 1024 + i];
        colsum[i] = v;
    }
    __syncthreads();
    if (tid < 64) {
        int carry = 0;
        for (int c = 0; c < nb; c += 64) {
            int idx = c + tid;
            int v = (idx < nb) ? colsum[idx] : 0;
            int orig = v;
#pragma unroll
            for (int off = 1; off < 64; off <<= 1) {
                int y = __shfl_up(v, off, 64);
                if (tid >= off) v += y;
            }
            if (idx < nb) { int ex = carry + v - orig; bstart[idx] = ex; bcur[idx] = ex; }
            carry += __shfl(v, 63, 64);
        }
        if (tid == 0) bstart[nb] = E;
    }
}

__global__ __launch_bounds__(512)
void bucket_group(const int* __restrict__ src, const int* __restrict__ tgt,
                  int* __restrict__ bcur, int2* __restrict__ stage, int E, int nb)
{
    __shared__ int2 eb[EPB];                       // 64 KB
    __shared__ int hist[1024], lofs[1024], lcur[1024], gbase[1024];
    int base = blockIdx.x * EPB;
    int tid = threadIdx.x;
    for (int i = tid; i < nb; i += 512) { hist[i] = 0; lcur[i] = 0; }
    __syncthreads();
    int end = min(base + EPB, E);
    for (int e = base + tid; e < end; e += 512)
        atomicAdd(&hist[tgt[e] >> 6], 1);
    __syncthreads();
    if (tid < 64) {
        int carry = 0;
        for (int c = 0; c < nb; c += 64) {
            int idx = c + tid;
            int v = (idx < nb) ? hist[idx] : 0;
            int orig = v;
#pragma unroll
            for (int off = 1; off < 64; off <<= 1) {
                int y = __shfl_up(v, off, 64);
                if (tid >= off) v += y;
            }
            if (idx < nb) lofs[idx] = carry + v - orig;
            carry += __shfl(v, 63, 64);
        }
    }
    __syncthreads();
    for (int e = base + tid; e < end; e += 512) {
        int t = tgt[e], b = t >> 6;
        int r = atomicAdd(&lcur[b], 1);
        eb[lofs[b] + r] = make_int2(src[e], t);
    }
    __syncthreads();
    for (int i = tid; i < nb; i += 512)
        if (hist[i] > 0) gbase[i] = atomicAdd(&bcur[i], hist[i]);
    __syncthreads();
    int cnt = end - base;
    for (int i = tid; i < cnt; i += 512) {
        int2 v = eb[i];
        int b = v.y >> 6;
        stage[gbase[b] + (i - lofs[b])] = v;
    }
}

// One block per bucket: local CSR (writes rowp slice), LDS counting sort,
// coalesced src-only write.
__global__ __launch_bounds__(256)
void bucket_sort(const int2* __restrict__ stage, const int* __restrict__ bstart,
                 int* __restrict__ rowp, int* __restrict__ ssrc, int n, int nb)
{
    __shared__ int2 eb[3072], eb2[3072];           // 48 KB
    __shared__ int tcnt[64], tofs[64], tcur[64];
    int b = blockIdx.x;
    int t0 = b << 6;
    if (t0 >= n) return;
    int t1 = min(t0 + 64, n);
    int s0 = bstart[b], s1 = bstart[b + 1];
    int cnt = s1 - s0;
    int tid = threadIdx.x;
    if (tid < 64) { tcnt[tid] = 0; tcur[tid] = 0; }
    __syncthreads();
    bool fits = (cnt <= 3072);
    if (fits) {
        for (int i = tid; i < cnt; i += 256) {
            int2 v = stage[s0 + i];
            eb[i] = v;
            atomicAdd(&tcnt[v.y - t0], 1);
        }
    } else {
        for (int i = tid; i < cnt; i += 256)
            atomicAdd(&tcnt[stage[s0 + i].y - t0], 1);
    }
    __syncthreads();
    if (tid < 64) {
        int v = tcnt[tid], orig = v;
#pragma unroll
        for (int off = 1; off < 64; off <<= 1) {
            int y = __shfl_up(v, off, 64);
            if (tid >= off) v += y;
        }
        tofs[tid] = v - orig;                      // exclusive
        int t = t0 + tid;
        if (t < t1) rowp[t] = s0 + v - orig;
        if (t == n - 1) rowp[n] = s1;
    }
    __syncthreads();
    if (fits) {
        for (int i = tid; i < cnt; i += 256) {
            int2 v = eb[i];
            int lt = v.y - t0;
            int r = atomicAdd(&tcur[lt], 1);
            eb2[tofs[lt] + r] = v;
        }
        __syncthreads();
        for (int i = tid; i < cnt; i += 256) ssrc[s0 + i] = eb2[i].x;
    } else {
        for (int i = tid; i < cnt; i += 256) {
            int2 v = stage[s0 + i];
            int lt = v.y - t0;
            int r = atomicAdd(&tcur[lt], 1);
            ssrc[s0 + tofs[lt] + r] = v.x;
        }
    }
}

// ---------------------------------------------------------------------------
// Fully fused edge attention: wave per target. K|V adjacent in qkv -> one
// contiguous 512B gather per edge: lanes 0-31 carry K (4 dims each, 4-lane
// head teams), lanes 32-63 carry V. Head dot via 2x shfl_xor in K half; one
// __shfl(p, lane&31) mirrors scores to V lanes. Online softmax in registers;
// V lanes accumulate 4 dims. Scores never touch memory.
// ---------------------------------------------------------------------------
#define SCORE_SCALE 0.360673760222241f   // 0.25 * log2(e)

__global__ __launch_bounds__(256)
void attn_fused(const unsigned short* __restrict__ qkv, const int* __restrict__ rowp,
                const int* __restrict__ ssrc, unsigned short* __restrict__ agg,
                int n, int npad)
{
    int wid  = (blockIdx.x * blockDim.x + threadIdx.x) >> 6;
    int lane = threadIdx.x & 63;
    if (wid >= npad) return;
    const int j4 = lane & 31;
    if (wid >= n) {
        if (lane >= 32)
            *(uint2*)(agg + (size_t)wid * 128 + (size_t)(lane - 32) * 4) = make_uint2(0u, 0u);
        return;
    }

    // Q dims 4*j4 .. 4*j4+3, pre-scaled by 0.25*log2(e)
    uint2 qw = *(const uint2*)(qkv + (size_t)wid * 384 + j4 * 4);
    const float q0 = blo(qw.x) * SCORE_SCALE, q1 = bhi(qw.x) * SCORE_SCALE;
    const float q2 = blo(qw.y) * SCORE_SCALE, q3 = bhi(qw.y) * SCORE_SCALE;

    int e = rowp[wid];
    const int e1 = rowp[wid + 1];

    float m = -1e30f, s = 0.f, a0 = 0.f, a1 = 0.f, a2 = 0.f, a3 = 0.f;

    for (; e + 4 <= e1; e += 4) {
        int s0 = ssrc[e], s1 = ssrc[e + 1], s2 = ssrc[e + 2], s3 = ssrc[e + 3];
        uint2 k0 = *(const uint2*)(qkv + (size_t)s0 * 384 + 128 + lane * 4);
        uint2 k1 = *(const uint2*)(qkv + (size_t)s1 * 384 + 128 + lane * 4);
        uint2 k2 = *(const uint2*)(qkv + (size_t)s2 * 384 + 128 + lane * 4);
        uint2 k3 = *(const uint2*)(qkv + (size_t)s3 * 384 + 128 + lane * 4);
        float p0 = q0 * blo(k0.x) + q1 * bhi(k0.x) + q2 * blo(k0.y) + q3 * bhi(k0.y);
        float p1 = q0 * blo(k1.x) + q1 * bhi(k1.x) + q2 * blo(k1.y) + q3 * bhi(k1.y);
        float p2 = q0 * blo(k2.x) + q1 * bhi(k2.x) + q2 * blo(k2.y) + q3 * bhi(k2.y);
        float p3 = q0 * blo(k3.x) + q1 * bhi(k3.x) + q2 * blo(k3.y) + q3 * bhi(k3.y);
        p0 += __shfl_xor(p0, 1, 64); p0 += __shfl_xor(p0, 2, 64);
        p1 += __shfl_xor(p1, 1, 64); p1 += __shfl_xor(p1, 2, 64);
        p2 += __shfl_xor(p2, 1, 64); p2 += __shfl_xor(p2, 2, 64);
        p3 += __shfl_xor(p3, 1, 64); p3 += __shfl_xor(p3, 2, 64);
        float sc0 = __shfl(p0, j4, 64);
        float sc1 = __shfl(p1, j4, 64);
        float sc2 = __shfl(p2, j4, 64);
        float sc3 = __shfl(p3, j4, 64);
        float mn = fmaxf(fmaxf(fmaxf(sc0, sc1), fmaxf(sc2, sc3)), m);
        float scale = exp2f(m - mn);
        float w0 = exp2f(sc0 - mn), w1 = exp2f(sc1 - mn);
        float w2 = exp2f(sc2 - mn), w3 = exp2f(sc3 - mn);
        s  = s * scale + ((w0 + w1) + (w2 + w3));
        a0 = a0 * scale + (w0 * blo(k0.x) + w1 * blo(k1.x)) + (w2 * blo(k2.x) + w3 * blo(k3.x));
        a1 = a1 * scale + (w0 * bhi(k0.x) + w1 * bhi(k1.x)) + (w2 * bhi(k2.x) + w3 * bhi(k3.x));
        a2 = a2 * scale + (w0 * blo(k0.y) + w1 * blo(k1.y)) + (w2 * blo(k2.y) + w3 * blo(k3.y));
        a3 = a3 * scale + (w0 * bhi(k0.y) + w1 * bhi(k1.y)) + (w2 * bhi(k2.y) + w3 * bhi(k3.y));
        m = mn;
    }
    for (; e < e1; ++e) {
        int sx = ssrc[e];
        uint2 kv = *(const uint2*)(qkv + (size_t)sx * 384 + 128 + lane * 4);
        float p = q0 * blo(kv.x) + q1 * bhi(kv.x) + q2 * blo(kv.y) + q3 * bhi(kv.y);
        p += __shfl_xor(p, 1, 64); p += __shfl_xor(p, 2, 64);
        float sc = __shfl(p, j4, 64);
        float mn = fmaxf(m, sc);
        float scale = exp2f(m - mn);
        float w = exp2f(sc - mn);
        s  = s * scale + w;
        a0 = a0 * scale + w * blo(kv.x);
        a1 = a1 * scale + w * bhi(kv.x);
        a2 = a2 * scale + w * blo(kv.y);
        a3 = a3 * scale + w * bhi(kv.y);
        m = mn;
    }
    float inv = 1.f / (s + 1e-16f);
    if (lane >= 32) {
        unsigned int o1 = (unsigned int)f2b(a0 * inv) | ((unsigned int)f2b(a1 * inv) << 16);
        unsigned int o2 = (unsigned int)f2b(a2 * inv) | ((unsigned int)f2b(a3 * inv) << 16);
        *(uint2*)(agg + (size_t)wid * 128 + (size_t)(lane - 32) * 4) = make_uint2(o1, o2);
    }
}

// ---------------------------------------------------------------------------
extern "C" void kernel_launch(void* const* d_in, const int* in_sizes, int n_in,
                              void* d_out, int out_size, void* d_ws, size_t ws_size,
                              hipStream_t stream)
{
    const float* x    = (const float*)d_in[0];
    const float* Wq   = (const float*)d_in[1];
    const float* bq   = (const float*)d_in[2];
    const float* Wk   = (const float*)d_in[3];
    const float* bk   = (const float*)d_in[4];
    const float* Wv   = (const float*)d_in[5];
    const float* bv   = (const float*)d_in[6];
    const float* Wo   = (const float*)d_in[7];
    const float* bo   = (const float*)d_in[8];
    const float* ln1g = (const float*)d_in[9];
    const float* ln1b = (const float*)d_in[10];
    const float* W1   = (const float*)d_in[11];
    const float* b1   = (const float*)d_in[12];
    const float* W2   = (const float*)d_in[13];
    const float* b2   = (const float*)d_in[14];
    const float* ln2g = (const float*)d_in[15];
    const float* ln2b = (const float*)d_in[16];
    const int*   eidx = (const int*)d_in[17];

    const int N_ = in_sizes[0] / 128;
    const int E_ = in_sizes[17] / 2;
    const int Mpad = ((N_ + 127) / 128) * 128;
    const int nb = (N_ + 63) >> 6;                 // buckets of 64 targets (<=1024)
    const int* srcE = eidx;
    const int* tgtE = eidx + E_;
    float* out = (float*)d_out;

    // workspace layout
    unsigned short* xb   = (unsigned short*)d_ws;                 // [Mpad][128]
    unsigned short* qkvb = xb + (size_t)Mpad * 128;               // [Mpad][384]
    unsigned short* tb   = xb;                                    // alias [Mpad][512] (FF1 phase; xb dead)
    unsigned short* aggb = qkvb + (size_t)Mpad * 384;             // [Mpad][128]
    unsigned short* hb   = aggb + (size_t)Mpad * 128;             // [Mpad][128]
    unsigned short* WcatT = hb + (size_t)Mpad * 128;
    unsigned short* WoT  = WcatT + 384 * 128;
    unsigned short* W1T  = WoT + 128 * 128;
    unsigned short* W2T  = W1T + 512 * 128;
    float* bqkv          = (float*)(W2T + 128 * 512);
    int2* stage          = (int2*)(bqkv + 384);                   // [E]
    int* ssrc   = (int*)(stage + E_);                             // [E]
    int* bstart = ssrc + E_;                                      // [1025]
    int* bcur   = bstart + 1025;                                  // [1024]
    int* rowp   = bcur + 1024;                                    // [N+1]
    int* bhist  = rowp + N_ + 1;                                  // [gblocks*1024]

    const int xblocks = (int)(((size_t)Mpad * 128 / 4 + 255) / 256);
    const int gblocks = (E_ + EPB - 1) / EPB;

    cast_all<<<xblocks + 768 + gblocks, 256, 0, stream>>>(
        x, xb, N_, Mpad, xblocks,
        Wq, Wk, Wv, Wo, W1, W2, bq, bk, bv,
        WcatT, WoT, W1T, W2T, bqkv, tgtE, bhist, E_, nb);

    // QKV fused GEMM: [Mpad x 128] @ [128 x 384]
    mfma_gemm<128, 2><<<dim3(Mpad / 128, 3), 256, 0, stream>>>(
        xb, WcatT, bqkv, nullptr, nullptr, nullptr, qkvb, N_, 384);

    // edge sort by target
    bucket_scan<<<1, 256, 0, stream>>>(bhist, bstart, bcur, nb, gblocks, E_);
    bucket_group<<<gblocks, 512, 0, stream>>>(srcE, tgtE, bcur, stage, E_, nb);
    bucket_sort<<<nb, 256, 0, stream>>>(stage, bstart, rowp, ssrc, N_, nb);

    // fused attention (scores never hit memory)
    attn_fused<<<(Mpad + 3) / 4, 256, 0, stream>>>(qkvb, rowp, ssrc, aggb, N_, Mpad);

    // Wo GEMM + residual(x) + LN1 -> hb (bf16)
    mfma_gemm<128, 3><<<dim3(Mpad / 128, 1), 256, 0, stream>>>(
        aggb, WoT, bo, x, ln1g, ln1b, hb, N_, 128);

    // FF1: relu(h @ W1 + b1) -> tb (bf16)
    mfma_gemm<128, 1><<<dim3(Mpad / 128, 4), 256, 0, stream>>>(
        hb, W1T, b1, nullptr, nullptr, nullptr, tb, N_, 512);

    // FF2 + residual(hb) + LN2 -> out (f32)
    mfma_gemm<512, 4><<<dim3(Mpad / 128, 1), 256, 0, stream>>>(
        tb, W2T, b2, hb, ln2g, ln2b, out, N_, 128);
}

// Round 10
// 224.551 us; speedup vs baseline: 1.1427x; 1.1427x over previous
//
#include <hip/hip_runtime.h>
#include <math.h>

typedef __attribute__((ext_vector_type(8))) short bf16x8;
typedef __attribute__((ext_vector_type(4))) float f32x4;

__device__ __forceinline__ unsigned short f2b(float f) {
    unsigned int u = __float_as_uint(f);
    unsigned int r = (u + 0x7fffu + ((u >> 16) & 1u)) >> 16;   // RTNE
    return (unsigned short)r;
}
__device__ __forceinline__ float blo(unsigned int w) { return __uint_as_float(w << 16); }
__device__ __forceinline__ float bhi(unsigned int w) { return __uint_as_float(w & 0xffff0000u); }
__device__ __forceinline__ float b2f(unsigned short u) { return __uint_as_float((unsigned int)u << 16); }

__device__ __forceinline__ void gload_lds16(const void* g, void* lds) {
    __builtin_amdgcn_global_load_lds(
        (const __attribute__((address_space(1))) unsigned int*)g,
        (__attribute__((address_space(3))) unsigned int*)lds, 16, 0, 0);
}

// ---------------------------------------------------------------------------
// bf16 MFMA GEMM: out[M x NC] = epi(A[Mpad x K] @ W[K x NC] + bias)
// BT = W^T row-major [NC x K] bf16. Tile 128x128, BK=64, 4 waves, T2 swizzle.
// Single-buffered LDS (32 KB) -- 64KB double-buffer costs occupancy (r6).
// EPI: 1 = relu -> bf16 ws (unguarded, Mpad rows)
//      2 = bias -> bf16 ws (unguarded, Mpad rows)
//      3 = +res(f32) + LayerNorm -> bf16 ws (pad rows zeroed)   [NC==128]
//      4 = +res(bf16) + LayerNorm -> f32 out (guard row<M)      [NC==128]
// ---------------------------------------------------------------------------
template<int K, int EPI>
__global__ __launch_bounds__(256)
void mfma_gemm(const unsigned short* __restrict__ A,
               const unsigned short* __restrict__ BT,
               const float* __restrict__ bias,
               const void* __restrict__ res,
               const float* __restrict__ lng,
               const float* __restrict__ lnb,
               void* __restrict__ outv, int M, int NC)
{
    __shared__ unsigned short As[128 * 64];
    __shared__ unsigned short Bs[128 * 64];
    const int tid  = threadIdx.x;
    const int lane = tid & 63;
    const int wid  = tid >> 6;
    const int wr = wid >> 1, wc = wid & 1;
    const int rowBase = blockIdx.x * 128;
    const int colBase = blockIdx.y * 128;

    f32x4 acc[4][4];
#pragma unroll
    for (int i = 0; i < 4; ++i)
#pragma unroll
        for (int j = 0; j < 4; ++j) acc[i][j] = (f32x4)0.f;

    int srow[4], skoff[4];
#pragma unroll
    for (int t = 0; t < 4; ++t) {
        int c = tid + t * 256;
        int r = c >> 3, cc = c & 7;
        srow[t]  = r;
        skoff[t] = ((cc ^ (r & 7)) << 3);
    }

    const int rl = lane & 15;
    const int kh = lane >> 4;

    for (int k0 = 0; k0 < K; k0 += 64) {
#pragma unroll
        for (int t = 0; t < 4; ++t) {
            int c = tid + t * 256;
            gload_lds16(A + (size_t)(rowBase + srow[t]) * K + k0 + skoff[t], &As[c * 8]);
            gload_lds16(BT + (size_t)(colBase + srow[t]) * K + k0 + skoff[t], &Bs[c * 8]);
        }
        __syncthreads();

        bf16x8 a[4][2], b[4][2];
#pragma unroll
        for (int mi = 0; mi < 4; ++mi)
#pragma unroll
            for (int kt = 0; kt < 2; ++kt) {
                a[mi][kt] = *(const bf16x8*)&As[(((wr * 64 + mi * 16 + rl) * 64) + kt * 32 + kh * 8) ^ ((rl & 7) << 3)];
                b[mi][kt] = *(const bf16x8*)&Bs[(((wc * 64 + mi * 16 + rl) * 64) + kt * 32 + kh * 8) ^ ((rl & 7) << 3)];
            }
#pragma unroll
        for (int kt = 0; kt < 2; ++kt)
#pragma unroll
            for (int mi = 0; mi < 4; ++mi)
#pragma unroll
                for (int ni = 0; ni < 4; ++ni)
                    acc[mi][ni] = __builtin_amdgcn_mfma_f32_16x16x32_bf16(a[mi][kt], b[ni][kt], acc[mi][ni], 0, 0, 0);
        __syncthreads();
    }

    if (EPI == 3 || EPI == 4) {
        float* ls = (float*)As;
        float bb[4], gg[4], be[4];
#pragma unroll
        for (int ni = 0; ni < 4; ++ni) {
            int col = wc * 64 + ni * 16 + rl;
            bb[ni] = bias[col];
            gg[ni] = lng[col];
            be[ni] = lnb[col];
        }
#pragma unroll
        for (int mi = 0; mi < 4; ++mi) {
#pragma unroll
            for (int r = 0; r < 4; ++r) {
                int lrow = wr * 64 + mi * 16 + kh * 4 + r;
                int row  = rowBase + lrow;
                float s = 0.f, ss = 0.f;
#pragma unroll
                for (int ni = 0; ni < 4; ++ni) {
                    int col = wc * 64 + ni * 16 + rl;
                    float rr = 0.f;
                    if (row < M) {
                        if (EPI == 3) rr = ((const float*)res)[(size_t)row * 128 + col];
                        else          rr = b2f(((const unsigned short*)res)[(size_t)row * 128 + col]);
                    }
                    float v = acc[mi][ni][r] + bb[ni] + rr;
                    acc[mi][ni][r] = v;
                    s += v; ss += v * v;
                }
#pragma unroll
                for (int off = 1; off < 16; off <<= 1) {
                    s  += __shfl_xor(s,  off, 64);
                    ss += __shfl_xor(ss, off, 64);
                }
                if (rl == 0) {
                    ls[lrow * 2 + wc]       = s;
                    ls[256 + lrow * 2 + wc] = ss;
                }
            }
        }
        __syncthreads();
#pragma unroll
        for (int mi = 0; mi < 4; ++mi) {
#pragma unroll
            for (int r = 0; r < 4; ++r) {
                int lrow = wr * 64 + mi * 16 + kh * 4 + r;
                int row  = rowBase + lrow;
                float s  = ls[lrow * 2] + ls[lrow * 2 + 1];
                float ss = ls[256 + lrow * 2] + ls[256 + lrow * 2 + 1];
                float mean = s * (1.f / 128.f);
                float var  = ss * (1.f / 128.f) - mean * mean;
                float rstd = rsqrtf(var + 1e-5f);
#pragma unroll
                for (int ni = 0; ni < 4; ++ni) {
                    int col = wc * 64 + ni * 16 + rl;
                    float o = (acc[mi][ni][r] - mean) * rstd * gg[ni] + be[ni];
                    if (EPI == 3) {
                        ((unsigned short*)outv)[(size_t)row * 128 + col] = (row < M) ? f2b(o) : (unsigned short)0;
                    } else {
                        if (row < M) ((float*)outv)[(size_t)row * 128 + col] = o;
                    }
                }
            }
        }
    } else {
#pragma unroll
        for (int ni = 0; ni < 4; ++ni) {
            const int col = colBase + wc * 64 + ni * 16 + rl;
            const float bv = bias[col];
#pragma unroll
            for (int mi = 0; mi < 4; ++mi) {
                const int rowb = rowBase + wr * 64 + mi * 16 + kh * 4;
#pragma unroll
                for (int r = 0; r < 4; ++r) {
                    float v = acc[mi][ni][r] + bv;
                    if (EPI == 1) v = fmaxf(v, 0.f);
                    ((unsigned short*)outv)[(size_t)(rowb + r) * NC + col] = f2b(v);
                }
            }
        }
    }
}

// ---------------------------------------------------------------------------
// fused input casts + bcnt zeroing
// ---------------------------------------------------------------------------
__global__ void cast_all(const float* __restrict__ x, unsigned short* __restrict__ xb,
                         int n, int npad, int xblocks,
                         const float* __restrict__ Wq, const float* __restrict__ Wk,
                         const float* __restrict__ Wv, const float* __restrict__ Wo,
                         const float* __restrict__ W1, const float* __restrict__ W2,
                         const float* __restrict__ bq, const float* __restrict__ bk,
                         const float* __restrict__ bv,
                         unsigned short* __restrict__ WcatT, unsigned short* __restrict__ WoT,
                         unsigned short* __restrict__ W1T, unsigned short* __restrict__ W2T,
                         float* __restrict__ bqkv, int* __restrict__ bcnt)
{
    if (blockIdx.x < (unsigned)xblocks) {
        size_t i = ((size_t)blockIdx.x * 256 + threadIdx.x) * 4;
        if (i >= (size_t)npad * 128) return;
        float4 v = make_float4(0.f, 0.f, 0.f, 0.f);
        if (i < (size_t)n * 128) v = *(const float4*)(x + i);
        ushort4 o;
        o.x = f2b(v.x); o.y = f2b(v.y); o.z = f2b(v.z); o.w = f2b(v.w);
        *(ushort4*)(xb + i) = o;
        return;
    }
    int i = (blockIdx.x - xblocks) * 256 + threadIdx.x;
    if (i < 49152) {
        int j = i >> 7, k = i & 127;
        const float* W = (j < 128) ? Wq : ((j < 256) ? Wk : Wv);
        WcatT[i] = f2b(W[k * 128 + (j & 127)]);
    } else if (i < 65536) {
        int t = i - 49152; int j = t >> 7, k = t & 127;
        WoT[t] = f2b(Wo[k * 128 + j]);
    } else if (i < 131072) {
        int t = i - 65536; int j = t >> 7, k = t & 127;
        W1T[t] = f2b(W1[k * 512 + j]);
    } else if (i < 196608) {
        int t = i - 131072; int j = t >> 9, k = t & 511;
        W2T[t] = f2b(W2[k * 128 + j]);
    }
    if (i < 384) bqkv[i] = (i < 128) ? bq[i] : ((i < 256) ? bk[i - 128] : bv[i - 256]);
    if (i < 1024) bcnt[i] = 0;
}

// ---------------------------------------------------------------------------
// Bucketed counting sort of edges by target (bucket = 64 targets).
// ---------------------------------------------------------------------------
#define EPB 8192   // edges per grouping block

__global__ __launch_bounds__(512)
void bucket_count(const int* __restrict__ tgt, int* __restrict__ bcnt, int E, int nb)
{
    __shared__ int hist[1024];
    int base = blockIdx.x * EPB;
    for (int i = threadIdx.x; i < nb; i += 512) hist[i] = 0;
    __syncthreads();
    int end = min(base + EPB, E);
    for (int e = base + threadIdx.x; e < end; e += 512)
        atomicAdd(&hist[tgt[e] >> 6], 1);
    __syncthreads();
    for (int i = threadIdx.x; i < nb; i += 512)
        if (hist[i] > 0) atomicAdd(&bcnt[i], hist[i]);
}

__global__ __launch_bounds__(64)
void bucket_scan(const int* __restrict__ bcnt, int* __restrict__ bstart,
                 int* __restrict__ bcur, int nb, int E)
{
    int lane = threadIdx.x;
    int carry = 0;
    for (int c = 0; c < nb; c += 64) {
        int idx = c + lane;
        int v = (idx < nb) ? bcnt[idx] : 0;
        int orig = v;
#pragma unroll
        for (int off = 1; off < 64; off <<= 1) {
            int y = __shfl_up(v, off, 64);
            if (lane >= off) v += y;
        }
        if (idx < nb) { int ex = carry + v - orig; bstart[idx] = ex; bcur[idx] = ex; }
        carry += __shfl(v, 63, 64);
    }
    if (lane == 0) bstart[nb] = E;
}

__global__ __launch_bounds__(512)
void bucket_group(const int* __restrict__ src, const int* __restrict__ tgt,
                  int* __restrict__ bcur, int2* __restrict__ stage, int E, int nb)
{
    __shared__ int2 eb[EPB];                       // 64 KB
    __shared__ int hist[1024], lofs[1024], lcur[1024], gbase[1024];
    int base = blockIdx.x * EPB;
    int tid = threadIdx.x;
    for (int i = tid; i < nb; i += 512) { hist[i] = 0; lcur[i] = 0; }
    __syncthreads();
    int end = min(base + EPB, E);
    for (int e = base + tid; e < end; e += 512)
        atomicAdd(&hist[tgt[e] >> 6], 1);
    __syncthreads();
    if (tid < 64) {
        int carry = 0;
        for (int c = 0; c < nb; c += 64) {
            int idx = c + tid;
            int v = (idx < nb) ? hist[idx] : 0;
            int orig = v;
#pragma unroll
            for (int off = 1; off < 64; off <<= 1) {
                int y = __shfl_up(v, off, 64);
                if (tid >= off) v += y;
            }
            if (idx < nb) lofs[idx] = carry + v - orig;
            carry += __shfl(v, 63, 64);
        }
    }
    __syncthreads();
    for (int e = base + tid; e < end; e += 512) {
        int t = tgt[e], b = t >> 6;
        int r = atomicAdd(&lcur[b], 1);
        eb[lofs[b] + r] = make_int2(src[e], t);
    }
    __syncthreads();
    for (int i = tid; i < nb; i += 512)
        if (hist[i] > 0) gbase[i] = atomicAdd(&bcur[i], hist[i]);
    __syncthreads();
    int cnt = end - base;
    for (int i = tid; i < cnt; i += 512) {
        int2 v = eb[i];
        int b = v.y >> 6;
        stage[gbase[b] + (i - lofs[b])] = v;
    }
}

__global__ __launch_bounds__(256)
void bucket_sort(const int2* __restrict__ stage, const int* __restrict__ bstart,
                 int* __restrict__ rowp, int2* __restrict__ epos, int n, int nb)
{
    __shared__ int2 eb[3072], eb2[3072];           // 48 KB
    __shared__ int tcnt[64], tofs[64], tcur[64];
    int b = blockIdx.x;
    int t0 = b << 6;
    if (t0 >= n) return;
    int t1 = min(t0 + 64, n);
    int s0 = bstart[b], s1 = bstart[b + 1];
    int cnt = s1 - s0;
    int tid = threadIdx.x;
    if (tid < 64) { tcnt[tid] = 0; tcur[tid] = 0; }
    __syncthreads();
    bool fits = (cnt <= 3072);
    if (fits) {
        for (int i = tid; i < cnt; i += 256) {
            int2 v = stage[s0 + i];
            eb[i] = v;
            atomicAdd(&tcnt[v.y - t0], 1);
        }
    } else {
        for (int i = tid; i < cnt; i += 256)
            atomicAdd(&tcnt[stage[s0 + i].y - t0], 1);
    }
    __syncthreads();
    if (tid < 64) {
        int v = tcnt[tid], orig = v;
#pragma unroll
        for (int off = 1; off < 64; off <<= 1) {
            int y = __shfl_up(v, off, 64);
            if (tid >= off) v += y;
        }
        tofs[tid] = v - orig;                      // exclusive
        int t = t0 + tid;
        if (t < t1) rowp[t] = s0 + v - orig;
        if (t == n - 1) rowp[n] = s1;
    }
    __syncthreads();
    if (fits) {
        for (int i = tid; i < cnt; i += 256) {
            int2 v = eb[i];
            int lt = v.y - t0;
            int r = atomicAdd(&tcur[lt], 1);
            eb2[tofs[lt] + r] = v;
        }
        __syncthreads();
        for (int i = tid; i < cnt; i += 256) epos[s0 + i] = eb2[i];
    } else {
        for (int i = tid; i < cnt; i += 256) {
            int2 v = stage[s0 + i];
            int lt = v.y - t0;
            int r = atomicAdd(&tcur[lt], 1);
            epos[s0 + tofs[lt] + r] = v;
        }
    }
}

// ---------------------------------------------------------------------------
// Edge-parallel score kernel: 16 lanes per sorted edge. Writes UNNORMALIZED
// softmax weights exp2(score*log2e/4) as bf16 (no max pass: |score| <~ 8 so
// exp is safe in f32; softmax is shift-invariant so result matches ref).
// ---------------------------------------------------------------------------
#define SCORE_SCALE 0.360673760222241f   // 0.25 * log2(e)

__global__ __launch_bounds__(256)
void score_kernel(const unsigned short* __restrict__ qkv, const int2* __restrict__ epos,
                  unsigned short* __restrict__ wexp, int E)
{
    int gw = (blockIdx.x * 256 + threadIdx.x) >> 4;
    int el = threadIdx.x & 15;
    if (gw >= E) return;
    int2 st = epos[gw];
    uint4 qv = *(const uint4*)(qkv + (size_t)st.y * 384 + el * 8);
    uint4 kv = *(const uint4*)(qkv + (size_t)st.x * 384 + 128 + el * 8);
    float d;
    d  = blo(qv.x) * blo(kv.x) + bhi(qv.x) * bhi(kv.x);
    d += blo(qv.y) * blo(kv.y) + bhi(qv.y) * bhi(kv.y);
    d += blo(qv.z) * blo(kv.z) + bhi(qv.z) * bhi(kv.z);
    d += blo(qv.w) * blo(kv.w) + bhi(qv.w) * bhi(kv.w);
    d += __shfl_xor(d, 1, 64);
    if ((el & 1) == 0)
        wexp[(size_t)gw * 8 + (el >> 1)] = f2b(exp2f(d * SCORE_SCALE));
}

// ---------------------------------------------------------------------------
// Aggregation: TWO waves per target (contiguous half edge-ranges), no max
// tracking (weights pre-exp'd). Lane holds dims 2l,2l+1; head = lane>>3;
// per-lane partial (s, a0, a1) merged through LDS, half 0 writes output.
// ---------------------------------------------------------------------------
__global__ __launch_bounds__(256)
void attn_agg(const unsigned short* __restrict__ qkv, const int* __restrict__ rowp,
              const int2* __restrict__ epos, const unsigned short* __restrict__ wexp,
              unsigned short* __restrict__ agg, int n, int npad)
{
    __shared__ float ls[2][2][192];   // [target-in-block][half][a0a1(128) | s(64)]
    const int tid  = threadIdx.x;
    const int lane = tid & 63;
    const int half = (tid >> 6) & 1;
    const int tin  = tid >> 7;
    const int wid  = blockIdx.x * 2 + tin;
    const int head = lane >> 3;

    float s = 0.f, a0 = 0.f, a1 = 0.f;
    if (wid < n) {
        const int r0 = rowp[wid], r1 = rowp[wid + 1];
        const int mid = r0 + ((r1 - r0 + 1) >> 1);
        int e = half ? mid : r0;
        const int ee = half ? r1 : mid;
        for (; e + 4 <= ee; e += 4) {
            int s0 = epos[e].x, s1 = epos[e + 1].x, s2 = epos[e + 2].x, s3 = epos[e + 3].x;
            float w0 = b2f(wexp[(size_t)e * 8 + head]);
            float w1 = b2f(wexp[(size_t)(e + 1) * 8 + head]);
            float w2 = b2f(wexp[(size_t)(e + 2) * 8 + head]);
            float w3 = b2f(wexp[(size_t)(e + 3) * 8 + head]);
            unsigned int v0 = *(const unsigned int*)(qkv + (size_t)s0 * 384 + 256 + lane * 2);
            unsigned int v1 = *(const unsigned int*)(qkv + (size_t)s1 * 384 + 256 + lane * 2);
            unsigned int v2 = *(const unsigned int*)(qkv + (size_t)s2 * 384 + 256 + lane * 2);
            unsigned int v3 = *(const unsigned int*)(qkv + (size_t)s3 * 384 + 256 + lane * 2);
            s  += (w0 + w1) + (w2 + w3);
            a0 += (w0 * blo(v0) + w1 * blo(v1)) + (w2 * blo(v2) + w3 * blo(v3));
            a1 += (w0 * bhi(v0) + w1 * bhi(v1)) + (w2 * bhi(v2) + w3 * bhi(v3));
        }
        for (; e < ee; ++e) {
            int sx = epos[e].x;
            float w = b2f(wexp[(size_t)e * 8 + head]);
            unsigned int vw = *(const unsigned int*)(qkv + (size_t)sx * 384 + 256 + lane * 2);
            s  += w;
            a0 += w * blo(vw);
            a1 += w * bhi(vw);
        }
    }
    ls[tin][half][lane * 2]     = a0;
    ls[tin][half][lane * 2 + 1] = a1;
    ls[tin][half][128 + lane]   = s;
    __syncthreads();
    if (half == 0 && wid < npad) {
        if (wid >= n) {
            *(unsigned int*)(agg + (size_t)wid * 128 + lane * 2) = 0u;
        } else {
            a0 += ls[tin][1][lane * 2];
            a1 += ls[tin][1][lane * 2 + 1];
            s  += ls[tin][1][128 + lane];
            float inv = 1.f / (s + 1e-16f);
            unsigned int o = (unsigned int)f2b(a0 * inv) | ((unsigned int)f2b(a1 * inv) << 16);
            *(unsigned int*)(agg + (size_t)wid * 128 + lane * 2) = o;
        }
    }
}

// ---------------------------------------------------------------------------
extern "C" void kernel_launch(void* const* d_in, const int* in_sizes, int n_in,
                              void* d_out, int out_size, void* d_ws, size_t ws_size,
                              hipStream_t stream)
{
    const float* x    = (const float*)d_in[0];
    const float* Wq   = (const float*)d_in[1];
    const float* bq   = (const float*)d_in[2];
    const float* Wk   = (const float*)d_in[3];
    const float* bk   = (const float*)d_in[4];
    const float* Wv   = (const float*)d_in[5];
    const float* bv   = (const float*)d_in[6];
    const float* Wo   = (const float*)d_in[7];
    const float* bo   = (const float*)d_in[8];
    const float* ln1g = (const float*)d_in[9];
    const float* ln1b = (const float*)d_in[10];
    const float* W1   = (const float*)d_in[11];
    const float* b1   = (const float*)d_in[12];
    const float* W2   = (const float*)d_in[13];
    const float* b2   = (const float*)d_in[14];
    const float* ln2g = (const float*)d_in[15];
    const float* ln2b = (const float*)d_in[16];
    const int*   eidx = (const int*)d_in[17];

    const int N_ = in_sizes[0] / 128;
    const int E_ = in_sizes[17] / 2;
    const int Mpad = ((N_ + 127) / 128) * 128;
    const int nb = (N_ + 63) >> 6;                 // buckets of 64 targets (<=1024)
    const int* srcE = eidx;
    const int* tgtE = eidx + E_;
    float* out = (float*)d_out;

    // workspace layout
    unsigned short* xb   = (unsigned short*)d_ws;                 // [Mpad][128]
    unsigned short* qkvb = xb + (size_t)Mpad * 128;               // [Mpad][384]
    unsigned short* tb   = xb;                                    // alias [Mpad][512] (FF1 phase; xb dead)
    unsigned short* aggb = qkvb + (size_t)Mpad * 384;             // [Mpad][128]
    unsigned short* hb   = aggb + (size_t)Mpad * 128;             // [Mpad][128]
    unsigned short* wexp = hb + (size_t)Mpad * 128;               // [E][8] bf16 exp-weights
    unsigned short* WcatT = wexp + (size_t)E_ * 8;
    unsigned short* WoT  = WcatT + 384 * 128;
    unsigned short* W1T  = WoT + 128 * 128;
    unsigned short* W2T  = W1T + 512 * 128;
    float* bqkv          = (float*)(W2T + 128 * 512);
    int2* stage          = (int2*)(bqkv + 384);                   // [E]
    int2* epos           = stage + E_;                            // [E]
    int* bcnt   = (int*)(epos + E_);                              // [1024]
    int* bstart = bcnt + 1024;                                    // [1025]
    int* bcur   = bstart + 1025;                                  // [1024]
    int* rowp   = bcur + 1024;                                    // [N+1]

    const int xblocks = (int)(((size_t)Mpad * 128 / 4 + 255) / 256);
    const int gblocks = (E_ + EPB - 1) / EPB;

    cast_all<<<xblocks + 768, 256, 0, stream>>>(x, xb, N_, Mpad, xblocks,
                                                Wq, Wk, Wv, Wo, W1, W2, bq, bk, bv,
                                                WcatT, WoT, W1T, W2T, bqkv, bcnt);

    // QKV fused GEMM: [Mpad x 128] @ [128 x 384]
    mfma_gemm<128, 2><<<dim3(Mpad / 128, 3), 256, 0, stream>>>(
        xb, WcatT, bqkv, nullptr, nullptr, nullptr, qkvb, N_, 384);

    // edge sort by target
    bucket_count<<<gblocks, 512, 0, stream>>>(tgtE, bcnt, E_, nb);
    bucket_scan<<<1, 64, 0, stream>>>(bcnt, bstart, bcur, nb, E_);
    bucket_group<<<gblocks, 512, 0, stream>>>(srcE, tgtE, bcur, stage, E_, nb);
    bucket_sort<<<nb, 256, 0, stream>>>(stage, bstart, rowp, epos, N_, nb);

    // attention: exp-weights then 2-wave-per-target weighted gather
    score_kernel<<<((size_t)E_ * 16 + 255) / 256, 256, 0, stream>>>(qkvb, epos, wexp, E_);
    attn_agg<<<Mpad / 2, 256, 0, stream>>>(qkvb, rowp, epos, wexp, aggb, N_, Mpad);

    // Wo GEMM + residual(x) + LN1 -> hb (bf16)
    mfma_gemm<128, 3><<<dim3(Mpad / 128, 1), 256, 0, stream>>>(
        aggb, WoT, bo, x, ln1g, ln1b, hb, N_, 128);

    // FF1: relu(h @ W1 + b1) -> tb (bf16)
    mfma_gemm<128, 1><<<dim3(Mpad / 128, 4), 256, 0, stream>>>(
        hb, W1T, b1, nullptr, nullptr, nullptr, tb, N_, 512);

    // FF2 + residual(hb) + LN2 -> out (f32)
    mfma_gemm<512, 4><<<dim3(Mpad / 128, 1), 256, 0, stream>>>(
        tb, W2T, b2, hb, ln2g, ln2b, out, N_, 128);
}

// Round 11
// 208.041 us; speedup vs baseline: 1.2334x; 1.0794x over previous
//
#include <hip/hip_runtime.h>
#include <math.h>

typedef __attribute__((ext_vector_type(8))) short bf16x8;
typedef __attribute__((ext_vector_type(4))) float f32x4;

__device__ __forceinline__ unsigned short f2b(float f) {
    unsigned int u = __float_as_uint(f);
    unsigned int r = (u + 0x7fffu + ((u >> 16) & 1u)) >> 16;   // RTNE
    return (unsigned short)r;
}
__device__ __forceinline__ float blo(unsigned int w) { return __uint_as_float(w << 16); }
__device__ __forceinline__ float bhi(unsigned int w) { return __uint_as_float(w & 0xffff0000u); }
__device__ __forceinline__ float b2f(unsigned short u) { return __uint_as_float((unsigned int)u << 16); }

__device__ __forceinline__ void gload_lds16(const void* g, void* lds) {
    __builtin_amdgcn_global_load_lds(
        (const __attribute__((address_space(1))) unsigned int*)g,
        (__attribute__((address_space(3))) unsigned int*)lds, 16, 0, 0);
}

// ---------------------------------------------------------------------------
// bf16 MFMA GEMM: out[M x NC] = epi(A[Mpad x K] @ W[K x NC] + bias)
// BT = W^T row-major [NC x K] bf16. Tile 128x128, BK=64, 4 waves, T2 swizzle.
// Single-buffered LDS (32 KB) -- 64KB double-buffer costs occupancy (r6).
// EPI: 1 = relu -> bf16 ws (unguarded, Mpad rows)
//      2 = bias -> bf16 ws (unguarded, Mpad rows)
//      3 = +res(f32) + LayerNorm -> bf16 ws (pad rows zeroed)   [NC==128]
//      4 = +res(bf16) + LayerNorm -> f32 out (guard row<M)      [NC==128]
// ---------------------------------------------------------------------------
template<int K, int EPI>
__global__ __launch_bounds__(256)
void mfma_gemm(const unsigned short* __restrict__ A,
               const unsigned short* __restrict__ BT,
               const float* __restrict__ bias,
               const void* __restrict__ res,
               const float* __restrict__ lng,
               const float* __restrict__ lnb,
               void* __restrict__ outv, int M, int NC)
{
    __shared__ unsigned short As[128 * 64];
    __shared__ unsigned short Bs[128 * 64];
    const int tid  = threadIdx.x;
    const int lane = tid & 63;
    const int wid  = tid >> 6;
    const int wr = wid >> 1, wc = wid & 1;
    const int rowBase = blockIdx.x * 128;
    const int colBase = blockIdx.y * 128;

    f32x4 acc[4][4];
#pragma unroll
    for (int i = 0; i < 4; ++i)
#pragma unroll
        for (int j = 0; j < 4; ++j) acc[i][j] = (f32x4)0.f;

    int srow[4], skoff[4];
#pragma unroll
    for (int t = 0; t < 4; ++t) {
        int c = tid + t * 256;
        int r = c >> 3, cc = c & 7;
        srow[t]  = r;
        skoff[t] = ((cc ^ (r & 7)) << 3);
    }

    const int rl = lane & 15;
    const int kh = lane >> 4;

    for (int k0 = 0; k0 < K; k0 += 64) {
#pragma unroll
        for (int t = 0; t < 4; ++t) {
            int c = tid + t * 256;
            gload_lds16(A + (size_t)(rowBase + srow[t]) * K + k0 + skoff[t], &As[c * 8]);
            gload_lds16(BT + (size_t)(colBase + srow[t]) * K + k0 + skoff[t], &Bs[c * 8]);
        }
        __syncthreads();

        bf16x8 a[4][2], b[4][2];
#pragma unroll
        for (int mi = 0; mi < 4; ++mi)
#pragma unroll
            for (int kt = 0; kt < 2; ++kt) {
                a[mi][kt] = *(const bf16x8*)&As[(((wr * 64 + mi * 16 + rl) * 64) + kt * 32 + kh * 8) ^ ((rl & 7) << 3)];
                b[mi][kt] = *(const bf16x8*)&Bs[(((wc * 64 + mi * 16 + rl) * 64) + kt * 32 + kh * 8) ^ ((rl & 7) << 3)];
            }
#pragma unroll
        for (int kt = 0; kt < 2; ++kt)
#pragma unroll
            for (int mi = 0; mi < 4; ++mi)
#pragma unroll
                for (int ni = 0; ni < 4; ++ni)
                    acc[mi][ni] = __builtin_amdgcn_mfma_f32_16x16x32_bf16(a[mi][kt], b[ni][kt], acc[mi][ni], 0, 0, 0);
        __syncthreads();
    }

    if (EPI == 3 || EPI == 4) {
        float* ls = (float*)As;
        float bb[4], gg[4], be[4];
#pragma unroll
        for (int ni = 0; ni < 4; ++ni) {
            int col = wc * 64 + ni * 16 + rl;
            bb[ni] = bias[col];
            gg[ni] = lng[col];
            be[ni] = lnb[col];
        }
#pragma unroll
        for (int mi = 0; mi < 4; ++mi) {
#pragma unroll
            for (int r = 0; r < 4; ++r) {
                int lrow = wr * 64 + mi * 16 + kh * 4 + r;
                int row  = rowBase + lrow;
                float s = 0.f, ss = 0.f;
#pragma unroll
                for (int ni = 0; ni < 4; ++ni) {
                    int col = wc * 64 + ni * 16 + rl;
                    float rr = 0.f;
                    if (row < M) {
                        if (EPI == 3) rr = ((const float*)res)[(size_t)row * 128 + col];
                        else          rr = b2f(((const unsigned short*)res)[(size_t)row * 128 + col]);
                    }
                    float v = acc[mi][ni][r] + bb[ni] + rr;
                    acc[mi][ni][r] = v;
                    s += v; ss += v * v;
                }
#pragma unroll
                for (int off = 1; off < 16; off <<= 1) {
                    s  += __shfl_xor(s,  off, 64);
                    ss += __shfl_xor(ss, off, 64);
                }
                if (rl == 0) {
                    ls[lrow * 2 + wc]       = s;
                    ls[256 + lrow * 2 + wc] = ss;
                }
            }
        }
        __syncthreads();
#pragma unroll
        for (int mi = 0; mi < 4; ++mi) {
#pragma unroll
            for (int r = 0; r < 4; ++r) {
                int lrow = wr * 64 + mi * 16 + kh * 4 + r;
                int row  = rowBase + lrow;
                float s  = ls[lrow * 2] + ls[lrow * 2 + 1];
                float ss = ls[256 + lrow * 2] + ls[256 + lrow * 2 + 1];
                float mean = s * (1.f / 128.f);
                float var  = ss * (1.f / 128.f) - mean * mean;
                float rstd = rsqrtf(var + 1e-5f);
#pragma unroll
                for (int ni = 0; ni < 4; ++ni) {
                    int col = wc * 64 + ni * 16 + rl;
                    float o = (acc[mi][ni][r] - mean) * rstd * gg[ni] + be[ni];
                    if (EPI == 3) {
                        ((unsigned short*)outv)[(size_t)row * 128 + col] = (row < M) ? f2b(o) : (unsigned short)0;
                    } else {
                        if (row < M) ((float*)outv)[(size_t)row * 128 + col] = o;
                    }
                }
            }
        }
    } else {
#pragma unroll
        for (int ni = 0; ni < 4; ++ni) {
            const int col = colBase + wc * 64 + ni * 16 + rl;
            const float bv = bias[col];
#pragma unroll
            for (int mi = 0; mi < 4; ++mi) {
                const int rowb = rowBase + wr * 64 + mi * 16 + kh * 4;
#pragma unroll
                for (int r = 0; r < 4; ++r) {
                    float v = acc[mi][ni][r] + bv;
                    if (EPI == 1) v = fmaxf(v, 0.f);
                    ((unsigned short*)outv)[(size_t)(rowb + r) * NC + col] = f2b(v);
                }
            }
        }
    }
}

// ---------------------------------------------------------------------------
// fused input casts + bcnt zeroing
// ---------------------------------------------------------------------------
__global__ void cast_all(const float* __restrict__ x, unsigned short* __restrict__ xb,
                         int n, int npad, int xblocks,
                         const float* __restrict__ Wq, const float* __restrict__ Wk,
                         const float* __restrict__ Wv, const float* __restrict__ Wo,
                         const float* __restrict__ W1, const float* __restrict__ W2,
                         const float* __restrict__ bq, const float* __restrict__ bk,
                         const float* __restrict__ bv,
                         unsigned short* __restrict__ WcatT, unsigned short* __restrict__ WoT,
                         unsigned short* __restrict__ W1T, unsigned short* __restrict__ W2T,
                         float* __restrict__ bqkv, int* __restrict__ bcnt)
{
    if (blockIdx.x < (unsigned)xblocks) {
        size_t i = ((size_t)blockIdx.x * 256 + threadIdx.x) * 4;
        if (i >= (size_t)npad * 128) return;
        float4 v = make_float4(0.f, 0.f, 0.f, 0.f);
        if (i < (size_t)n * 128) v = *(const float4*)(x + i);
        ushort4 o;
        o.x = f2b(v.x); o.y = f2b(v.y); o.z = f2b(v.z); o.w = f2b(v.w);
        *(ushort4*)(xb + i) = o;
        return;
    }
    int i = (blockIdx.x - xblocks) * 256 + threadIdx.x;
    if (i < 49152) {
        int j = i >> 7, k = i & 127;
        const float* W = (j < 128) ? Wq : ((j < 256) ? Wk : Wv);
        WcatT[i] = f2b(W[k * 128 + (j & 127)]);
    } else if (i < 65536) {
        int t = i - 49152; int j = t >> 7, k = t & 127;
        WoT[t] = f2b(Wo[k * 128 + j]);
    } else if (i < 131072) {
        int t = i - 65536; int j = t >> 7, k = t & 127;
        W1T[t] = f2b(W1[k * 512 + j]);
    } else if (i < 196608) {
        int t = i - 131072; int j = t >> 9, k = t & 511;
        W2T[t] = f2b(W2[k * 128 + j]);
    }
    if (i < 384) bqkv[i] = (i < 128) ? bq[i] : ((i < 256) ? bk[i - 128] : bv[i - 256]);
    if (i < 1024) bcnt[i] = 0;
}

// ---------------------------------------------------------------------------
// Bucketed counting sort of edges by target (bucket = 64 targets).
// ---------------------------------------------------------------------------
#define EPB 8192   // edges per grouping block

__global__ __launch_bounds__(512)
void bucket_count(const int* __restrict__ tgt, int* __restrict__ bcnt, int E, int nb)
{
    __shared__ int hist[1024];
    int base = blockIdx.x * EPB;
    for (int i = threadIdx.x; i < nb; i += 512) hist[i] = 0;
    __syncthreads();
    int end = min(base + EPB, E);
    for (int e = base + threadIdx.x; e < end; e += 512)
        atomicAdd(&hist[tgt[e] >> 6], 1);
    __syncthreads();
    for (int i = threadIdx.x; i < nb; i += 512)
        if (hist[i] > 0) atomicAdd(&bcnt[i], hist[i]);
}

__global__ __launch_bounds__(64)
void bucket_scan(const int* __restrict__ bcnt, int* __restrict__ bstart,
                 int* __restrict__ bcur, int nb, int E)
{
    int lane = threadIdx.x;
    int carry = 0;
    for (int c = 0; c < nb; c += 64) {
        int idx = c + lane;
        int v = (idx < nb) ? bcnt[idx] : 0;
        int orig = v;
#pragma unroll
        for (int off = 1; off < 64; off <<= 1) {
            int y = __shfl_up(v, off, 64);
            if (lane >= off) v += y;
        }
        if (idx < nb) { int ex = carry + v - orig; bstart[idx] = ex; bcur[idx] = ex; }
        carry += __shfl(v, 63, 64);
    }
    if (lane == 0) bstart[nb] = E;
}

__global__ __launch_bounds__(512)
void bucket_group(const int* __restrict__ src, const int* __restrict__ tgt,
                  int* __restrict__ bcur, int2* __restrict__ stage, int E, int nb)
{
    __shared__ int2 eb[EPB];                       // 64 KB
    __shared__ int hist[1024], lofs[1024], lcur[1024], gbase[1024];
    int base = blockIdx.x * EPB;
    int tid = threadIdx.x;
    for (int i = tid; i < nb; i += 512) { hist[i] = 0; lcur[i] = 0; }
    __syncthreads();
    int end = min(base + EPB, E);
    for (int e = base + tid; e < end; e += 512)
        atomicAdd(&hist[tgt[e] >> 6], 1);
    __syncthreads();
    if (tid < 64) {
        int carry = 0;
        for (int c = 0; c < nb; c += 64) {
            int idx = c + tid;
            int v = (idx < nb) ? hist[idx] : 0;
            int orig = v;
#pragma unroll
            for (int off = 1; off < 64; off <<= 1) {
                int y = __shfl_up(v, off, 64);
                if (tid >= off) v += y;
            }
            if (idx < nb) lofs[idx] = carry + v - orig;
            carry += __shfl(v, 63, 64);
        }
    }
    __syncthreads();
    for (int e = base + tid; e < end; e += 512) {
        int t = tgt[e], b = t >> 6;
        int r = atomicAdd(&lcur[b], 1);
        eb[lofs[b] + r] = make_int2(src[e], t);
    }
    __syncthreads();
    for (int i = tid; i < nb; i += 512)
        if (hist[i] > 0) gbase[i] = atomicAdd(&bcur[i], hist[i]);
    __syncthreads();
    int cnt = end - base;
    for (int i = tid; i < cnt; i += 512) {
        int2 v = eb[i];
        int b = v.y >> 6;
        stage[gbase[b] + (i - lofs[b])] = v;
    }
}

__global__ __launch_bounds__(256)
void bucket_sort(const int2* __restrict__ stage, const int* __restrict__ bstart,
                 int* __restrict__ rowp, int2* __restrict__ epos, int n, int nb)
{
    __shared__ int2 eb[3072], eb2[3072];           // 48 KB
    __shared__ int tcnt[64], tofs[64], tcur[64];
    int b = blockIdx.x;
    int t0 = b << 6;
    if (t0 >= n) return;
    int t1 = min(t0 + 64, n);
    int s0 = bstart[b], s1 = bstart[b + 1];
    int cnt = s1 - s0;
    int tid = threadIdx.x;
    if (tid < 64) { tcnt[tid] = 0; tcur[tid] = 0; }
    __syncthreads();
    bool fits = (cnt <= 3072);
    if (fits) {
        for (int i = tid; i < cnt; i += 256) {
            int2 v = stage[s0 + i];
            eb[i] = v;
            atomicAdd(&tcnt[v.y - t0], 1);
        }
    } else {
        for (int i = tid; i < cnt; i += 256)
            atomicAdd(&tcnt[stage[s0 + i].y - t0], 1);
    }
    __syncthreads();
    if (tid < 64) {
        int v = tcnt[tid], orig = v;
#pragma unroll
        for (int off = 1; off < 64; off <<= 1) {
            int y = __shfl_up(v, off, 64);
            if (tid >= off) v += y;
        }
        tofs[tid] = v - orig;                      // exclusive
        int t = t0 + tid;
        if (t < t1) rowp[t] = s0 + v - orig;
        if (t == n - 1) rowp[n] = s1;
    }
    __syncthreads();
    if (fits) {
        for (int i = tid; i < cnt; i += 256) {
            int2 v = eb[i];
            int lt = v.y - t0;
            int r = atomicAdd(&tcur[lt], 1);
            eb2[tofs[lt] + r] = v;
        }
        __syncthreads();
        for (int i = tid; i < cnt; i += 256) epos[s0 + i] = eb2[i];
    } else {
        for (int i = tid; i < cnt; i += 256) {
            int2 v = stage[s0 + i];
            int lt = v.y - t0;
            int r = atomicAdd(&tcur[lt], 1);
            epos[s0 + tofs[lt] + r] = v;
        }
    }
}

// ---------------------------------------------------------------------------
// Edge-parallel score kernel: 16 lanes per sorted edge. Writes UNNORMALIZED
// softmax weights exp2(score*log2e/4) as bf16 (no max pass: |score| <~ 8 so
// exp is safe in f32; softmax is shift-invariant so result matches ref).
// ---------------------------------------------------------------------------
#define SCORE_SCALE 0.360673760222241f   // 0.25 * log2(e)

__global__ __launch_bounds__(256)
void score_kernel(const unsigned short* __restrict__ qkv, const int2* __restrict__ epos,
                  unsigned short* __restrict__ wexp, int E)
{
    int gw = (blockIdx.x * 256 + threadIdx.x) >> 4;
    int el = threadIdx.x & 15;
    if (gw >= E) return;
    int2 st = epos[gw];
    uint4 qv = *(const uint4*)(qkv + (size_t)st.y * 384 + el * 8);
    uint4 kv = *(const uint4*)(qkv + (size_t)st.x * 384 + 128 + el * 8);
    float d;
    d  = blo(qv.x) * blo(kv.x) + bhi(qv.x) * bhi(kv.x);
    d += blo(qv.y) * blo(kv.y) + bhi(qv.y) * bhi(kv.y);
    d += blo(qv.z) * blo(kv.z) + bhi(qv.z) * bhi(kv.z);
    d += blo(qv.w) * blo(kv.w) + bhi(qv.w) * bhi(kv.w);
    d += __shfl_xor(d, 1, 64);
    if ((el & 1) == 0)
        wexp[(size_t)gw * 8 + (el >> 1)] = f2b(exp2f(d * SCORE_SCALE));
}

// ---------------------------------------------------------------------------
// Aggregation: ONE wave per target (r6 structure -- 2-wave LDS merge was a
// regression), pure weighted V-gather with pre-exp'd bf16 weights, 8-edge
// unroll for deeper load ILP (latency-bound: VALU 46%, HBM 26% at r10).
// Lane holds dims 2l,2l+1; head = lane>>3.
// ---------------------------------------------------------------------------
__global__ __launch_bounds__(256)
void attn_agg(const unsigned short* __restrict__ qkv, const int* __restrict__ rowp,
              const int2* __restrict__ epos, const unsigned short* __restrict__ wexp,
              unsigned short* __restrict__ agg, int n, int npad)
{
    int wid  = (blockIdx.x * blockDim.x + threadIdx.x) >> 6;
    int lane = threadIdx.x & 63;
    if (wid >= npad) return;
    if (wid >= n) { *(unsigned int*)(agg + (size_t)wid * 128 + lane * 2) = 0u; return; }

    const int head = lane >> 3;
    int e = rowp[wid];
    const int e1 = rowp[wid + 1];

    float s = 0.f, a0 = 0.f, a1 = 0.f;

    for (; e + 8 <= e1; e += 8) {
        int sx[8];
        float w[8];
        unsigned int v[8];
#pragma unroll
        for (int u = 0; u < 8; ++u) sx[u] = epos[e + u].x;
#pragma unroll
        for (int u = 0; u < 8; ++u) w[u] = b2f(wexp[(size_t)(e + u) * 8 + head]);
#pragma unroll
        for (int u = 0; u < 8; ++u)
            v[u] = *(const unsigned int*)(qkv + (size_t)sx[u] * 384 + 256 + lane * 2);
#pragma unroll
        for (int u = 0; u < 8; ++u) {
            s  += w[u];
            a0 += w[u] * blo(v[u]);
            a1 += w[u] * bhi(v[u]);
        }
    }
    for (; e + 4 <= e1; e += 4) {
        int s0 = epos[e].x, s1 = epos[e + 1].x, s2 = epos[e + 2].x, s3 = epos[e + 3].x;
        float w0 = b2f(wexp[(size_t)e * 8 + head]);
        float w1 = b2f(wexp[(size_t)(e + 1) * 8 + head]);
        float w2 = b2f(wexp[(size_t)(e + 2) * 8 + head]);
        float w3 = b2f(wexp[(size_t)(e + 3) * 8 + head]);
        unsigned int v0 = *(const unsigned int*)(qkv + (size_t)s0 * 384 + 256 + lane * 2);
        unsigned int v1 = *(const unsigned int*)(qkv + (size_t)s1 * 384 + 256 + lane * 2);
        unsigned int v2 = *(const unsigned int*)(qkv + (size_t)s2 * 384 + 256 + lane * 2);
        unsigned int v3 = *(const unsigned int*)(qkv + (size_t)s3 * 384 + 256 + lane * 2);
        s  += (w0 + w1) + (w2 + w3);
        a0 += (w0 * blo(v0) + w1 * blo(v1)) + (w2 * blo(v2) + w3 * blo(v3));
        a1 += (w0 * bhi(v0) + w1 * bhi(v1)) + (w2 * bhi(v2) + w3 * bhi(v3));
    }
    for (; e < e1; ++e) {
        int sx = epos[e].x;
        float w = b2f(wexp[(size_t)e * 8 + head]);
        unsigned int vw = *(const unsigned int*)(qkv + (size_t)sx * 384 + 256 + lane * 2);
        s  += w;
        a0 += w * blo(vw);
        a1 += w * bhi(vw);
    }
    float inv = 1.f / (s + 1e-16f);
    unsigned int o = (unsigned int)f2b(a0 * inv) | ((unsigned int)f2b(a1 * inv) << 16);
    *(unsigned int*)(agg + (size_t)wid * 128 + lane * 2) = o;
}

// ---------------------------------------------------------------------------
extern "C" void kernel_launch(void* const* d_in, const int* in_sizes, int n_in,
                              void* d_out, int out_size, void* d_ws, size_t ws_size,
                              hipStream_t stream)
{
    const float* x    = (const float*)d_in[0];
    const float* Wq   = (const float*)d_in[1];
    const float* bq   = (const float*)d_in[2];
    const float* Wk   = (const float*)d_in[3];
    const float* bk   = (const float*)d_in[4];
    const float* Wv   = (const float*)d_in[5];
    const float* bv   = (const float*)d_in[6];
    const float* Wo   = (const float*)d_in[7];
    const float* bo   = (const float*)d_in[8];
    const float* ln1g = (const float*)d_in[9];
    const float* ln1b = (const float*)d_in[10];
    const float* W1   = (const float*)d_in[11];
    const float* b1   = (const float*)d_in[12];
    const float* W2   = (const float*)d_in[13];
    const float* b2   = (const float*)d_in[14];
    const float* ln2g = (const float*)d_in[15];
    const float* ln2b = (const float*)d_in[16];
    const int*   eidx = (const int*)d_in[17];

    const int N_ = in_sizes[0] / 128;
    const int E_ = in_sizes[17] / 2;
    const int Mpad = ((N_ + 127) / 128) * 128;
    const int nb = (N_ + 63) >> 6;                 // buckets of 64 targets (<=1024)
    const int* srcE = eidx;
    const int* tgtE = eidx + E_;
    float* out = (float*)d_out;

    // workspace layout
    unsigned short* xb   = (unsigned short*)d_ws;                 // [Mpad][128]
    unsigned short* qkvb = xb + (size_t)Mpad * 128;               // [Mpad][384]
    unsigned short* tb   = xb;                                    // alias [Mpad][512] (FF1 phase; xb dead)
    unsigned short* aggb = qkvb + (size_t)Mpad * 384;             // [Mpad][128]
    unsigned short* hb   = aggb + (size_t)Mpad * 128;             // [Mpad][128]
    unsigned short* wexp = hb + (size_t)Mpad * 128;               // [E][8] bf16 exp-weights
    unsigned short* WcatT = wexp + (size_t)E_ * 8;
    unsigned short* WoT  = WcatT + 384 * 128;
    unsigned short* W1T  = WoT + 128 * 128;
    unsigned short* W2T  = W1T + 512 * 128;
    float* bqkv          = (float*)(W2T + 128 * 512);
    int2* stage          = (int2*)(bqkv + 384);                   // [E]
    int2* epos           = stage + E_;                            // [E]
    int* bcnt   = (int*)(epos + E_);                              // [1024]
    int* bstart = bcnt + 1024;                                    // [1025]
    int* bcur   = bstart + 1025;                                  // [1024]
    int* rowp   = bcur + 1024;                                    // [N+1]

    const int xblocks = (int)(((size_t)Mpad * 128 / 4 + 255) / 256);
    const int gblocks = (E_ + EPB - 1) / EPB;

    cast_all<<<xblocks + 768, 256, 0, stream>>>(x, xb, N_, Mpad, xblocks,
                                                Wq, Wk, Wv, Wo, W1, W2, bq, bk, bv,
                                                WcatT, WoT, W1T, W2T, bqkv, bcnt);

    // QKV fused GEMM: [Mpad x 128] @ [128 x 384]
    mfma_gemm<128, 2><<<dim3(Mpad / 128, 3), 256, 0, stream>>>(
        xb, WcatT, bqkv, nullptr, nullptr, nullptr, qkvb, N_, 384);

    // edge sort by target
    bucket_count<<<gblocks, 512, 0, stream>>>(tgtE, bcnt, E_, nb);
    bucket_scan<<<1, 64, 0, stream>>>(bcnt, bstart, bcur, nb, E_);
    bucket_group<<<gblocks, 512, 0, stream>>>(srcE, tgtE, bcur, stage, E_, nb);
    bucket_sort<<<nb, 256, 0, stream>>>(stage, bstart, rowp, epos, N_, nb);

    // attention: exp-weights then 1-wave-per-target weighted gather
    score_kernel<<<((size_t)E_ * 16 + 255) / 256, 256, 0, stream>>>(qkvb, epos, wexp, E_);
    attn_agg<<<(Mpad + 3) / 4, 256, 0, stream>>>(qkvb, rowp, epos, wexp, aggb, N_, Mpad);

    // Wo GEMM + residual(x) + LN1 -> hb (bf16)
    mfma_gemm<128, 3><<<dim3(Mpad / 128, 1), 256, 0, stream>>>(
        aggb, WoT, bo, x, ln1g, ln1b, hb, N_, 128);

    // FF1: relu(h @ W1 + b1) -> tb (bf16)
    mfma_gemm<128, 1><<<dim3(Mpad / 128, 4), 256, 0, stream>>>(
        hb, W1T, b1, nullptr, nullptr, nullptr, tb, N_, 512);

    // FF2 + residual(hb) + LN2 -> out (f32)
    mfma_gemm<512, 4><<<dim3(Mpad / 128, 1), 256, 0, stream>>>(
        tb, W2T, b2, hb, ln2g, ln2b, out, N_, 128);
}